// Round 7
// baseline (184.254 us; speedup 1.0000x reference)
//
#include <hip/hip_runtime.h>

// SSIM loss, fused, R7.
// R6 post-mortem: <2 x float> packing scalarized (VALUBusy unchanged) -> no gain.
// R7: both conv passes in packed fp16 (v_pk_*_f16 via _Float16 ext-vectors, the
// reliably-emitted path). fp32 epilogue rescales all accumulators by 1/S^2
// (S = sum of quantized fp16 weights) to kill the weight-quantization
// systematic (measured x30 amplification through the sigma12 numerator).
// 5 blocks/CU (LDS 30.7KB, launch_bounds(256,5)). Single barrier.

typedef _Float16 f16;
typedef __attribute__((ext_vector_type(2))) _Float16 f16x2;
typedef __attribute__((ext_vector_type(4))) _Float16 f16x4;

constexpr int IMG_H = 512;
constexpr int IMG_W = 512;
constexpr int NBC   = 48;             // B*C planes
constexpr int TW    = 64;             // output tile width
constexpr int TH    = 32;             // output tile height
constexpr int HALO  = 5;
constexpr int NTAP  = 11;
constexpr int IH    = TH + 2*HALO;    // 42 h-rows
constexpr int SH    = TW + 8;         // 72 halves/row (144B): b64-aligned, benign banks
constexpr int NBLKX = IMG_W / TW;     // 8
constexpr int NBLKY = IMG_H / TH;     // 16
constexpr int NBLK  = NBLKX * NBLKY * NBC; // 6144
constexpr float C1 = 1.0e-4f;
constexpr float C2 = 9.0e-4f;

__device__ __forceinline__ f16x2 pk(float a, float b) {
    return __builtin_bit_cast(f16x2, __builtin_amdgcn_cvt_pkrtz(a, b));
}

__global__ __launch_bounds__(64) void ssim_init(double* acc) {
    if (threadIdx.x == 0) acc[0] = 0.0;
}

__global__ __launch_bounds__(256, 5) void ssim_main(const float* __restrict__ sr,
                                                    const float* __restrict__ hr,
                                                    double* __restrict__ sink,
                                                    int mode) {
    __shared__ f16 h1 [IH * SH];
    __shared__ f16 h2 [IH * SH];
    __shared__ f16 h11[IH * SH];
    __shared__ f16 h22[IH * SH];
    __shared__ f16 h12[IH * SH];
    __shared__ float wsums[4];

    // fp32 reference weights -> fp16 quantized + exact fp32 sum for rescale
    float gf[NTAP];
    {
        float gsum = 0.f;
#pragma unroll
        for (int i = 0; i < NTAP; ++i) {
            float d = (float)(i - HALO);
            gf[i] = __expf(-d * d / (2.0f * 1.5f * 1.5f));
            gsum += gf[i];
        }
#pragma unroll
        for (int i = 0; i < NTAP; ++i) gf[i] /= gsum;
    }
    f16x2 g2[NTAP];
    float S = 0.f;
#pragma unroll
    for (int i = 0; i < NTAP; ++i) {
        const f16 gh = (f16)gf[i];
        g2[i] = (f16x2){gh, gh};
        S += (float)gh;
    }
    const float inv2 = 1.f / (S * S);   // each quantity carries S (h) * S (v)

    const int bc      = blockIdx.z;
    const int gr0     = blockIdx.y * TH - HALO;  // global row of h-row 0
    const int gc_base = blockIdx.x * TW;         // global col of output col 0
    const float* __restrict__ srp = sr + (size_t)bc * IMG_H * IMG_W;
    const float* __restrict__ hrp = hr + (size_t)bc * IMG_H * IMG_W;

    // ---- horizontal pass: task = 1 h-row x 4 output cols, packed fp16 ----
    for (int tt = threadIdx.x; tt < IH * (TW / 4); tt += 256) { // 672 tasks
        const int r  = tt >> 4;
        const int cg = tt & 15;
        const int gr = gr0 + r;
        const int W0 = gc_base + cg * 4;
        f16x2 AB[20];                            // (sr,hr) fp16 pairs, cols W0-8..W0+11
        if ((unsigned)gr < (unsigned)IMG_H) {
            const float* __restrict__ ra = srp + (size_t)gr * IMG_W;
            const float* __restrict__ rb = hrp + (size_t)gr * IMG_W;
            if (W0 >= 8 && W0 <= 500) {          // interior: 5 aligned float4 each
                const float4* pa = (const float4*)&ra[W0 - 8];
                const float4* pb = (const float4*)&rb[W0 - 8];
                const float4 a0 = pa[0], a1v = pa[1], a2v = pa[2], a3v = pa[3], a4v = pa[4];
                const float4 b0 = pb[0], b1v = pb[1], b2v = pb[2], b3v = pb[3], b4v = pb[4];
                AB[0]  = pk(a0.x,  b0.x);  AB[1]  = pk(a0.y,  b0.y);
                AB[2]  = pk(a0.z,  b0.z);  AB[3]  = pk(a0.w,  b0.w);
                AB[4]  = pk(a1v.x, b1v.x); AB[5]  = pk(a1v.y, b1v.y);
                AB[6]  = pk(a1v.z, b1v.z); AB[7]  = pk(a1v.w, b1v.w);
                AB[8]  = pk(a2v.x, b2v.x); AB[9]  = pk(a2v.y, b2v.y);
                AB[10] = pk(a2v.z, b2v.z); AB[11] = pk(a2v.w, b2v.w);
                AB[12] = pk(a3v.x, b3v.x); AB[13] = pk(a3v.y, b3v.y);
                AB[14] = pk(a3v.z, b3v.z); AB[15] = pk(a3v.w, b3v.w);
                AB[16] = pk(a4v.x, b4v.x); AB[17] = pk(a4v.y, b4v.y);
                AB[18] = pk(a4v.z, b4v.z); AB[19] = pk(a4v.w, b4v.w);
            } else {                             // image-edge cols: guarded scalar
#pragma unroll
                for (int i = 0; i < 20; ++i) {
                    const int c = W0 - 8 + i;
                    const bool ok = (unsigned)c < (unsigned)IMG_W;
                    AB[i] = pk(ok ? ra[c] : 0.f, ok ? rb[c] : 0.f);
                }
            }
        } else {
#pragma unroll
            for (int i = 0; i < 20; ++i) AB[i] = (f16x2){(f16)0, (f16)0};
        }
        // per output col u: sm=(conv a, conv b), sq=(conv a^2, conv b^2), sp=conv ab
        f16x2 om[4], oq[4];
        f16 op[4];
#pragma unroll
        for (int u = 0; u < 4; ++u) {
            f16x2 sm = {(f16)0, (f16)0}, sq = {(f16)0, (f16)0};
            f16 sp = (f16)0;
#pragma unroll
            for (int k = 0; k < NTAP; ++k) {
                const f16x2 x  = AB[3 + u + k];
                const f16x2 ga = g2[k] * x;      // v_pk_mul_f16
                sm += ga;                        // v_pk_add_f16
                sq += ga * x;                    // v_pk_fma_f16
                sp += ga.x * x.y;                // v_fma_f16
            }
            om[u] = sm; oq[u] = sq; op[u] = sp;
        }
        const int ho = r * SH + cg * 4;          // 8B aligned
        *(f16x4*)&h1 [ho] = (f16x4){om[0].x, om[1].x, om[2].x, om[3].x};
        *(f16x4*)&h2 [ho] = (f16x4){om[0].y, om[1].y, om[2].y, om[3].y};
        *(f16x4*)&h11[ho] = (f16x4){oq[0].x, oq[1].x, oq[2].x, oq[3].x};
        *(f16x4*)&h22[ho] = (f16x4){oq[0].y, oq[1].y, oq[2].y, oq[3].y};
        *(f16x4*)&h12[ho] = (f16x4){op[0],   op[1],   op[2],   op[3]};
    }
    __syncthreads();

    // ---- vertical pass: 256 threads, 2 rows x 4 cols each, packed fp16 acc ----
    float local = 0.f;
    {
        const int cg = threadIdx.x & 15;
        const int rg = threadIdx.x >> 4;
        const int c0 = cg * 4;
        const int r0 = rg * 2;
        // acc[row][quantity][colpair]
        f16x2 acc[2][5][2] = {};
#pragma unroll
        for (int j = 0; j < 12; ++j) {           // h-rows r0 .. r0+11
            const int ho = (r0 + j) * SH + c0;
            const f16x4 x1  = *(const f16x4*)&h1 [ho];
            const f16x4 x2  = *(const f16x4*)&h2 [ho];
            const f16x4 x11 = *(const f16x4*)&h11[ho];
            const f16x4 x22 = *(const f16x4*)&h22[ho];
            const f16x4 x12 = *(const f16x4*)&h12[ho];
#pragma unroll
            for (int i = 0; i < 2; ++i) {
                if (j >= i && j <= i + 10) {
                    const f16x2 gk = g2[j - i];
                    acc[i][0][0] += gk * x1.lo;  acc[i][0][1] += gk * x1.hi;
                    acc[i][1][0] += gk * x2.lo;  acc[i][1][1] += gk * x2.hi;
                    acc[i][2][0] += gk * x11.lo; acc[i][2][1] += gk * x11.hi;
                    acc[i][3][0] += gk * x22.lo; acc[i][3][1] += gk * x22.hi;
                    acc[i][4][0] += gk * x12.lo; acc[i][4][1] += gk * x12.hi;
                }
            }
        }
        // fp32 epilogue with 1/S^2 rescale (kills weight-quantization systematic)
#pragma unroll
        for (int i = 0; i < 2; ++i) {
#pragma unroll
            for (int p = 0; p < 2; ++p) {
#pragma unroll
                for (int l = 0; l < 2; ++l) {
                    const float m1 = (l ? (float)acc[i][0][p].y : (float)acc[i][0][p].x) * inv2;
                    const float m2 = (l ? (float)acc[i][1][p].y : (float)acc[i][1][p].x) * inv2;
                    const float q1 = (l ? (float)acc[i][2][p].y : (float)acc[i][2][p].x) * inv2;
                    const float q2 = (l ? (float)acc[i][3][p].y : (float)acc[i][3][p].x) * inv2;
                    const float pp = (l ? (float)acc[i][4][p].y : (float)acc[i][4][p].x) * inv2;
                    const float mu1s = m1 * m1, mu2s = m2 * m2, mu12 = m1 * m2;
                    const float sg1  = q1 - mu1s;
                    const float sg2  = q2 - mu2s;
                    const float sg12 = pp - mu12;
                    const float num = (2.f * mu12 + C1) * (2.f * sg12 + C2);
                    const float den = (mu1s + mu2s + C1) * (sg1 + sg2 + C2) + 1e-12f;
                    local += num * __builtin_amdgcn_rcpf(den);
                }
            }
        }
    }

    // ---- block reduction ----
#pragma unroll
    for (int off = 32; off > 0; off >>= 1)
        local += __shfl_down(local, off, 64);
    const int lane = threadIdx.x & 63, wave = threadIdx.x >> 6;
    if (lane == 0) wsums[wave] = local;
    __syncthreads();
    if (threadIdx.x == 0) {
        const double bsum = (double)(wsums[0] + wsums[1] + wsums[2] + wsums[3]);
        if (mode == 0) {
            const int bid = (blockIdx.z * NBLKY + blockIdx.y) * NBLKX + blockIdx.x;
            sink[bid] = bsum;
        } else {
            atomicAdd(sink, bsum);
        }
    }
}

__global__ __launch_bounds__(256) void ssim_finalize(const double* __restrict__ partial,
                                                     float* __restrict__ out, int count) {
    __shared__ double ws[4];
    double s = 0.0;
    for (int i = threadIdx.x; i < count; i += 256) s += partial[i];
#pragma unroll
    for (int off = 32; off > 0; off >>= 1)
        s += __shfl_down(s, off, 64);
    const int lane = threadIdx.x & 63, wave = threadIdx.x >> 6;
    if (lane == 0) ws[wave] = s;
    __syncthreads();
    if (threadIdx.x == 0) {
        const double tot = ws[0] + ws[1] + ws[2] + ws[3];
        const double n = (double)NBC * IMG_H * IMG_W;
        out[0] = (float)(1.0 - tot / n);
    }
}

extern "C" void kernel_launch(void* const* d_in, const int* in_sizes, int n_in,
                              void* d_out, int out_size, void* d_ws, size_t ws_size,
                              hipStream_t stream) {
    const float* sr = (const float*)d_in[0];
    const float* hr = (const float*)d_in[1];
    float* out = (float*)d_out;
    const dim3 grid(NBLKX, NBLKY, NBC);

    if (ws_size >= (size_t)NBLK * sizeof(double)) {
        double* partial = (double*)d_ws; // fully overwritten each call
        ssim_main<<<grid, dim3(256), 0, stream>>>(sr, hr, partial, 0);
        ssim_finalize<<<dim3(1), dim3(256), 0, stream>>>(partial, out, NBLK);
    } else {
        double* acc = (double*)d_ws;
        ssim_init<<<dim3(1), dim3(64), 0, stream>>>(acc);
        ssim_main<<<grid, dim3(256), 0, stream>>>(sr, hr, acc, 1);
        ssim_finalize<<<dim3(1), dim3(256), 0, stream>>>(acc, out, 1);
    }
}